// Round 1
// baseline (152.306 us; speedup 1.0000x reference)
//
#include <hip/hip_runtime.h>
#include <math.h>

// VQC_Registers_BS_density: 16 layers of U rho U^T with U_l = G(th_l) (x) I
// (even l, row-register pairs) or I (x) G(th_l) (odd l, col-register pairs).
// G's 2x2 blocks M(th)=[[sin,cos],[-cos,sin]]=R(th-pi/2) are rotations on the
// SAME pair structure every layer with a scalar angle per layer, so the whole
// product collapses exactly to (R(SA) (x) R(SB)) rho (R(SA) (x) R(SB))^T with
// SA = sum of even-layer angles, SB = sum of odd-layer angles
// (8 factors of -pi/2 = -4pi = identity).
//
// Flat index of rho[s,t], s=r1*32+c1, t=r2*32+c2:
//   idx = r1*32768 + c1*1024 + r2*32 + c2
// The transform is 4 independent 2-point butterflies along the low bit of each
// of r1 (stride 32768), c1 (1024), r2 (32), c2 (1).
//
// This version: each thread owns a c2-QUAD (two c2 pairs, one float4) x r2
// pair x c1 pair x r1 pair = 32 elements, still closed under all four
// butterflies. All global traffic is dwordx4 (16 B/lane, 1 KiB/wave-instr),
// halving memory-instruction count vs the float2 version. 32768 threads,
// 256 blocks x 128 threads (one block per CU).

__global__ __launch_bounds__(128) void vqc_bs_density_kernel(
    const float* __restrict__ rho,
    const float* __restrict__ angles,
    float* __restrict__ out) {

    // Composed angles (wave-uniform; angles array is 64 B, L1-resident).
    float SA = 0.f, SB = 0.f;
#pragma unroll
    for (int l = 0; l < 16; l += 2) SA += angles[l];
#pragma unroll
    for (int l = 1; l < 16; l += 2) SB += angles[l];
    float ca, sa, cb, sb;
    sincosf(SA, &sa, &ca);
    sincosf(SB, &sb, &cb);

    const int gid = blockIdx.x * blockDim.x + threadIdx.x;  // 0..32767
    const int c2q = gid & 7;           // c2 = 4*c2q (one float4 = two c2 pairs)
    const int r2g = (gid >> 3) & 15;   // r2 = 2*r2g
    const int c1g = (gid >> 7) & 15;   // c1 = 2*c1g
    const int r1g = (gid >> 11) & 15;  // r1 = 2*r1g

    // Base element: low bits of r1,c1,r2 = 0; c2 quad-aligned (16B aligned).
    const int base = ((r1g * 2) * 32 + (c1g * 2)) * 1024 + (r2g * 2) * 32 + c2q * 4;

    // v[dr1][dc1][dr2][k], k = c2 offset 0..3 within the quad.
    float v[2][2][2][4];
#pragma unroll
    for (int dr1 = 0; dr1 < 2; ++dr1)
#pragma unroll
        for (int dc1 = 0; dc1 < 2; ++dc1)
#pragma unroll
            for (int dr2 = 0; dr2 < 2; ++dr2) {
                const float4 t = *(const float4*)(rho + base + dr1 * 32768 + dc1 * 1024 + dr2 * 32);
                v[dr1][dc1][dr2][0] = t.x;
                v[dr1][dc1][dr2][1] = t.y;
                v[dr1][dc1][dr2][2] = t.z;
                v[dr1][dc1][dr2][3] = t.w;
            }

    // Stage r1: rotation (ca,sa) along dr1.
#pragma unroll
    for (int dc1 = 0; dc1 < 2; ++dc1)
#pragma unroll
        for (int dr2 = 0; dr2 < 2; ++dr2)
#pragma unroll
            for (int k = 0; k < 4; ++k) {
                const float e = v[0][dc1][dr2][k];
                const float o = v[1][dc1][dr2][k];
                v[0][dc1][dr2][k] = ca * e - sa * o;
                v[1][dc1][dr2][k] = sa * e + ca * o;
            }

    // Stage c1: rotation (cb,sb) along dc1.
#pragma unroll
    for (int dr1 = 0; dr1 < 2; ++dr1)
#pragma unroll
        for (int dr2 = 0; dr2 < 2; ++dr2)
#pragma unroll
            for (int k = 0; k < 4; ++k) {
                const float e = v[dr1][0][dr2][k];
                const float o = v[dr1][1][dr2][k];
                v[dr1][0][dr2][k] = cb * e - sb * o;
                v[dr1][1][dr2][k] = sb * e + cb * o;
            }

    // Stage r2: rotation (ca,sa) along dr2.
#pragma unroll
    for (int dr1 = 0; dr1 < 2; ++dr1)
#pragma unroll
        for (int dc1 = 0; dc1 < 2; ++dc1)
#pragma unroll
            for (int k = 0; k < 4; ++k) {
                const float e = v[dr1][dc1][0][k];
                const float o = v[dr1][dc1][1][k];
                v[dr1][dc1][0][k] = ca * e - sa * o;
                v[dr1][dc1][1][k] = sa * e + ca * o;
            }

    // Stage c2: rotation (cb,sb) on pairs (0,1) and (2,3) within the quad.
#pragma unroll
    for (int dr1 = 0; dr1 < 2; ++dr1)
#pragma unroll
        for (int dc1 = 0; dc1 < 2; ++dc1)
#pragma unroll
            for (int dr2 = 0; dr2 < 2; ++dr2)
#pragma unroll
                for (int p = 0; p < 2; ++p) {
                    const float e = v[dr1][dc1][dr2][2 * p];
                    const float o = v[dr1][dc1][dr2][2 * p + 1];
                    v[dr1][dc1][dr2][2 * p] = cb * e - sb * o;
                    v[dr1][dc1][dr2][2 * p + 1] = sb * e + cb * o;
                }

    // Store (same addresses, separate output buffer), dwordx4.
#pragma unroll
    for (int dr1 = 0; dr1 < 2; ++dr1)
#pragma unroll
        for (int dc1 = 0; dc1 < 2; ++dc1)
#pragma unroll
            for (int dr2 = 0; dr2 < 2; ++dr2) {
                float4 t;
                t.x = v[dr1][dc1][dr2][0];
                t.y = v[dr1][dc1][dr2][1];
                t.z = v[dr1][dc1][dr2][2];
                t.w = v[dr1][dc1][dr2][3];
                *(float4*)(out + base + dr1 * 32768 + dc1 * 1024 + dr2 * 32) = t;
            }
}

extern "C" void kernel_launch(void* const* d_in, const int* in_sizes, int n_in,
                              void* d_out, int out_size, void* d_ws, size_t ws_size,
                              hipStream_t stream) {
    const float* rho = (const float*)d_in[0];     // input_state, 1024*1024 f32
    const float* angles = (const float*)d_in[1];  // 16 f32
    float* out = (float*)d_out;                   // 1024*1024 f32
    // 32768 threads, 32 elements each; 256 blocks x 128 threads (1 block/CU).
    vqc_bs_density_kernel<<<256, 128, 0, stream>>>(rho, angles, out);
}